// Round 1
// baseline (1557.062 us; speedup 1.0000x reference)
//
#include <hip/hip_runtime.h>
#include <stdint.h>

// ---------------------------------------------------------------------------
// Decoder: GRU(seq) + Bahdanau-ish attention + dense + vocab projection
// H=512, V=32000, B=16, Td=Te=64
// Round 1: correctness-first. fp32 everywhere except the logits GEMM
// (1024x32000, K=512) which uses bf16 MFMA 16x16x32 with fp32 accumulate.
// ---------------------------------------------------------------------------

#define Hdim 512
#define Vdim 32000
#define Bdim 16
#define Tdim 64
#define BT   1024   // B*Td rows

typedef __attribute__((ext_vector_type(8))) short bf16x8;
typedef __attribute__((ext_vector_type(4))) float f32x4;

static __device__ __forceinline__ unsigned short f2bf(float f) {
    unsigned u = __float_as_uint(f);
    u = u + 0x7FFFu + ((u >> 16) & 1u);   // round-to-nearest-even
    return (unsigned short)(u >> 16);
}

// --------------------------- small utility kernels -------------------------

__global__ void zero_kernel(float* p, int n) {
    int i = blockIdx.x * 256 + threadIdx.x;
    if (i < n) p[i] = 0.f;
}

__global__ void copy_kernel(const float* __restrict__ in, float* __restrict__ out, int n) {
    int i = blockIdx.x * 256 + threadIdx.x;
    if (i < n) out[i] = in[i];
}

__global__ void f32_to_bf16_kernel(const float* __restrict__ in, unsigned short* __restrict__ out, int n) {
    int i = blockIdx.x * 256 + threadIdx.x;
    int stride = gridDim.x * 256;
    for (; i < n; i += stride) out[i] = f2bf(in[i]);
}

// --------------------------- generic fp32 GEMM -----------------------------
// C[M x N] = act( A(M x K, lda) @ B(N x K, ldb)^T + bias ),  all dims %64==0, K%16==0
// grid = (N/64, M/64), block = 256

__global__ __launch_bounds__(256) void gemm_f32(
    const float* __restrict__ A, int lda,
    const float* __restrict__ B, int ldb,
    const float* __restrict__ bias,
    float* __restrict__ C, int ldc,
    int K, int act)
{
    __shared__ float As[16][68];
    __shared__ float Bs[16][68];
    const int tid = threadIdx.x;
    const int tx = tid & 15, ty = tid >> 4;
    const int m0 = blockIdx.y * 64, n0 = blockIdx.x * 64;

    float acc[4][4];
#pragma unroll
    for (int i = 0; i < 4; ++i)
#pragma unroll
        for (int j = 0; j < 4; ++j) acc[i][j] = 0.f;

    const int r  = tid >> 2;        // 0..63
    const int kq = (tid & 3) * 4;   // 0,4,8,12

    for (int k0 = 0; k0 < K; k0 += 16) {
        float4 a4 = *(const float4*)(A + (size_t)(m0 + r) * lda + k0 + kq);
        float4 b4 = *(const float4*)(B + (size_t)(n0 + r) * ldb + k0 + kq);
        As[kq + 0][r] = a4.x; As[kq + 1][r] = a4.y; As[kq + 2][r] = a4.z; As[kq + 3][r] = a4.w;
        Bs[kq + 0][r] = b4.x; Bs[kq + 1][r] = b4.y; Bs[kq + 2][r] = b4.z; Bs[kq + 3][r] = b4.w;
        __syncthreads();
#pragma unroll
        for (int k = 0; k < 16; ++k) {
            float4 av = *(const float4*)(&As[k][ty * 4]);
            float4 bv = *(const float4*)(&Bs[k][tx * 4]);
            acc[0][0] += av.x * bv.x; acc[0][1] += av.x * bv.y; acc[0][2] += av.x * bv.z; acc[0][3] += av.x * bv.w;
            acc[1][0] += av.y * bv.x; acc[1][1] += av.y * bv.y; acc[1][2] += av.y * bv.z; acc[1][3] += av.y * bv.w;
            acc[2][0] += av.z * bv.x; acc[2][1] += av.z * bv.y; acc[2][2] += av.z * bv.z; acc[2][3] += av.z * bv.w;
            acc[3][0] += av.w * bv.x; acc[3][1] += av.w * bv.y; acc[3][2] += av.w * bv.z; acc[3][3] += av.w * bv.w;
        }
        __syncthreads();
    }

    const float4 bv4 = *(const float4*)(bias + n0 + tx * 4);
#pragma unroll
    for (int i = 0; i < 4; ++i) {
        int row = m0 + ty * 4 + i;
        float4 v;
        v.x = acc[i][0] + bv4.x; v.y = acc[i][1] + bv4.y;
        v.z = acc[i][2] + bv4.z; v.w = acc[i][3] + bv4.w;
        if (act == 1) { v.x = tanhf(v.x); v.y = tanhf(v.y); v.z = tanhf(v.z); v.w = tanhf(v.w); }
        *(float4*)(C + (size_t)row * ldc + n0 + tx * 4) = v;
    }
}

// ------------------------------- GRU step ----------------------------------
// grid = 128 blocks (4 j's each), block = 192 threads (12 W_hh rows x 16 b)
// hp = h_in @ W_hh^T + b_hh ; gates ; h_out ; y -> cat[:, :512]

__global__ __launch_bounds__(192) void gru_step_kernel(
    const float* __restrict__ h_in, float* __restrict__ h_out,
    const float* __restrict__ xp,           // (1024,1536)
    const float* __restrict__ Whh,          // (1536,512)
    const float* __restrict__ bhh,          // (1536)
    const int* __restrict__ lengths,        // (16)
    float* __restrict__ cat,                // (1024,1024) write cols [0,512)
    int t)
{
    __shared__ float hp_lds[12 * 16];
    const int tid = threadIdx.x;
    const int rl = tid >> 4;     // 0..11
    const int b  = tid & 15;
    const int gate = rl >> 2, jj = rl & 3;
    const int j0 = blockIdx.x * 4;
    const int row = gate * 512 + j0 + jj;

    const float* w = Whh + (size_t)row * Hdim;
    const float* h = h_in + b * Hdim;
    float4 a4 = {0.f, 0.f, 0.f, 0.f};
#pragma unroll 4
    for (int k = 0; k < Hdim; k += 4) {
        float4 wv = *(const float4*)(w + k);
        float4 hv = *(const float4*)(h + k);
        a4.x += wv.x * hv.x; a4.y += wv.y * hv.y;
        a4.z += wv.z * hv.z; a4.w += wv.w * hv.w;
    }
    hp_lds[rl * 16 + b] = (a4.x + a4.y) + (a4.z + a4.w) + bhh[row];
    __syncthreads();

    if (tid < 64) {
        const int jj2 = tid >> 4, b2 = tid & 15;
        const int j = j0 + jj2;
        float hr = hp_lds[(0 + jj2) * 16 + b2];
        float hz = hp_lds[(4 + jj2) * 16 + b2];
        float hn = hp_lds[(8 + jj2) * 16 + b2];
        const float* xrow = xp + (size_t)(b2 * Tdim + t) * 1536;
        float xr = xrow[j], xz = xrow[512 + j], xn = xrow[1024 + j];
        float rg = 1.f / (1.f + __expf(-(xr + hr)));
        float zg = 1.f / (1.f + __expf(-(xz + hz)));
        float ng = tanhf(xn + rg * hn);
        float hold = h_in[b2 * Hdim + j];
        float hnew = (1.f - zg) * ng + zg * hold;
        bool valid = t < lengths[b2];
        h_out[b2 * Hdim + j] = valid ? hnew : hold;
        cat[(size_t)(b2 * Tdim + t) * 1024 + j] = valid ? hnew : 0.f;
    }
}

// ------------------------------ attention ----------------------------------
// one block per (b,d); energies -> softmax over valid e -> context
// writes cat[:, 512:1024]

__global__ __launch_bounds__(256) void attn_kernel(
    const float* __restrict__ encp,     // (1024,512)
    const float* __restrict__ decp,     // (1024,512)
    const float* __restrict__ enc,      // (16,64,512)
    const float* __restrict__ battn,    // (512)
    const float* __restrict__ vw,       // (512)
    const float* __restrict__ vb,       // (1)
    const int* __restrict__ enc_len,    // (16)
    const int* __restrict__ dec_len,    // (16)
    float* __restrict__ cat)            // (1024,1024)
{
    const int blk = blockIdx.x;
    const int b = blk >> 6, d = blk & 63;
    const int tid = threadIdx.x;
    float* ctx_out = cat + (size_t)(b * Tdim + d) * 1024 + 512;

    if (d >= dec_len[b]) {
        for (int h = tid; h < Hdim; h += 256) ctx_out[h] = 0.f;
        return;
    }
    const int Tv = enc_len[b];

    __shared__ float part[64][4];
    __shared__ float a_lds[64];

    const int e = tid >> 2, p = tid & 3;
    float s = 0.f;
    if (e < Tv) {
        const float* ep = encp + (size_t)(b * Tdim + e) * Hdim;
        const float* dp = decp + (size_t)(b * Tdim + d) * Hdim;
        const int g0 = p * 128;
        for (int g = g0; g < g0 + 128; ++g)
            s += vw[g] * tanhf(ep[g] + dp[g] + battn[g]);
    }
    part[e][p] = s;
    __syncthreads();

    if (tid < 64) {
        const int e2 = tid;
        float en = (e2 < Tv) ? (part[e2][0] + part[e2][1] + part[e2][2] + part[e2][3] + vb[0]) : -1e30f;
        float m = en;
#pragma unroll
        for (int off = 32; off; off >>= 1) m = fmaxf(m, __shfl_xor(m, off));
        float ex = (e2 < Tv) ? __expf(en - m) : 0.f;
        float sum = ex;
#pragma unroll
        for (int off = 32; off; off >>= 1) sum += __shfl_xor(sum, off);
        a_lds[e2] = ex / sum;
    }
    __syncthreads();

    const int h = tid * 2;
    float c0 = 0.f, c1 = 0.f;
    for (int e3 = 0; e3 < Tv; ++e3) {
        float a = a_lds[e3];
        float2 ev = *(const float2*)(enc + (size_t)(b * Tdim + e3) * Hdim + h);
        c0 += a * ev.x; c1 += a * ev.y;
    }
    float2 cv; cv.x = c0; cv.y = c1;
    *(float2*)(ctx_out + h) = cv;
}

// --------------------------- logits bf16 MFMA GEMM -------------------------
// C(1024 x 32000) = A(1024x512 bf16) @ B(32000x512 bf16)^T + bias, fp32 out
// 128x128 tile, BK=32, 4 waves, each wave 64x64 via 4x4 MFMA 16x16x32

__global__ __launch_bounds__(256) void gemm_logits(
    const unsigned short* __restrict__ A,
    const unsigned short* __restrict__ B,
    const float* __restrict__ bias,
    float* __restrict__ C)
{
    const int K = Hdim;
    __shared__ unsigned short As[128 * 40];
    __shared__ unsigned short Bs[128 * 40];
    const int tid = threadIdx.x;
    const int m0 = blockIdx.y * 128, n0 = blockIdx.x * 128;
    const int wave = tid >> 6, lane = tid & 63;
    const int wm = (wave >> 1) * 64, wn = (wave & 1) * 64;
    const int lrow = lane & 15, lk = (lane >> 4) * 8;

    f32x4 acc[4][4];
#pragma unroll
    for (int i = 0; i < 4; ++i)
#pragma unroll
        for (int j = 0; j < 4; ++j) acc[i][j] = (f32x4){0.f, 0.f, 0.f, 0.f};

    for (int k0 = 0; k0 < K; k0 += 32) {
#pragma unroll
        for (int i = 0; i < 2; ++i) {
            int idx = tid + i * 256;        // 0..511
            int rr = idx >> 2, kq = (idx & 3) * 8;
            *(uint4*)(&As[rr * 40 + kq]) = *(const uint4*)(A + (size_t)(m0 + rr) * K + k0 + kq);
            *(uint4*)(&Bs[rr * 40 + kq]) = *(const uint4*)(B + (size_t)(n0 + rr) * K + k0 + kq);
        }
        __syncthreads();
        bf16x8 af[4], bf[4];
#pragma unroll
        for (int i = 0; i < 4; ++i) af[i] = *(const bf16x8*)(&As[(wm + i * 16 + lrow) * 40 + lk]);
#pragma unroll
        for (int j = 0; j < 4; ++j) bf[j] = *(const bf16x8*)(&Bs[(wn + j * 16 + lrow) * 40 + lk]);
#pragma unroll
        for (int i = 0; i < 4; ++i)
#pragma unroll
            for (int j = 0; j < 4; ++j)
                acc[i][j] = __builtin_amdgcn_mfma_f32_16x16x32_bf16(af[i], bf[j], acc[i][j], 0, 0, 0);
        __syncthreads();
    }

    const int crow = m0 + wm + ((lane >> 4) * 4);
    const int ccol = n0 + wn + (lane & 15);
#pragma unroll
    for (int i = 0; i < 4; ++i) {
#pragma unroll
        for (int j = 0; j < 4; ++j) {
            int col = ccol + j * 16;
            float bv = bias[col];
#pragma unroll
            for (int rr = 0; rr < 4; ++rr) {
                int row = crow + i * 16 + rr;
                C[(size_t)row * Vdim + col] = acc[i][j][rr] + bv;
            }
        }
    }
}

// ------------------------------- launcher ----------------------------------

extern "C" void kernel_launch(void* const* d_in, const int* in_sizes, int n_in,
                              void* d_out, int out_size, void* d_ws, size_t ws_size,
                              hipStream_t stream) {
    (void)in_sizes; (void)n_in; (void)out_size; (void)ws_size;

    const float* input_seqs  = (const float*)d_in[0];
    const int*   input_len   = (const int*)  d_in[1];
    const float* enc_out     = (const float*)d_in[2];
    const int*   enc_len     = (const int*)  d_in[3];
    const float* W_ih        = (const float*)d_in[4];
    const float* W_hh        = (const float*)d_in[5];
    const float* b_ih        = (const float*)d_in[6];
    const float* b_hh        = (const float*)d_in[7];
    const float* W_attn      = (const float*)d_in[8];
    const float* b_attn      = (const float*)d_in[9];
    const float* v_w         = (const float*)d_in[10];
    const float* v_b         = (const float*)d_in[11];
    const float* W_dense     = (const float*)d_in[12];
    const float* b_dense     = (const float*)d_in[13];
    const float* W_out       = (const float*)d_in[14];
    const float* b_out       = (const float*)d_in[15];

    float* logits = (float*)d_out;                        // (1024, 32000)
    float* h_last = (float*)d_out + (size_t)BT * Vdim;    // (16, 512)

    // workspace layout (float slots)
    float* ws = (float*)d_ws;
    float* xp      = ws;                        // 1024*1536
    float* encp    = xp      + 1572864;         // 1024*512
    float* decp    = encp    + 524288;          // 1024*512
    float* cat     = decp    + 524288;          // 1024*1024
    float* dense   = cat     + 1048576;         // 1024*512
    float* h0      = dense   + 524288;          // 16*512
    float* h1      = h0      + 8192;            // 16*512
    unsigned short* Wout_bf  = (unsigned short*)(h1 + 8192);          // 32000*512 bf16
    unsigned short* dense_bf = Wout_bf + (size_t)Vdim * Hdim;         // 1024*512 bf16

    // 1. prep: zero h0, convert W_out -> bf16
    zero_kernel<<<32, 256, 0, stream>>>(h0, Bdim * Hdim);
    f32_to_bf16_kernel<<<2048, 256, 0, stream>>>(W_out, Wout_bf, Vdim * Hdim);

    // 2. x_proj = input_seqs @ W_ih^T + b_ih        (1024 x 1536, K=512)
    gemm_f32<<<dim3(1536 / 64, BT / 64), 256, 0, stream>>>(
        input_seqs, Hdim, W_ih, Hdim, b_ih, xp, 1536, Hdim, 0);

    // 3. enc_p = enc @ We^T   (We = W_attn[:, :512])  (1024 x 512, K=512)
    gemm_f32<<<dim3(Hdim / 64, BT / 64), 256, 0, stream>>>(
        enc_out, Hdim, W_attn, 1024, b_attn /*dummy? no: add 0*/, encp, Hdim, Hdim, 0);
    // NOTE: enc_p in the reference has NO bias; b_attn is added later in the
    // score. We must subtract it back -> instead pass a zero bias: reuse h0
    // (zeros, 8192 >= 512). Re-launch correctly below overwrites encp.
    gemm_f32<<<dim3(Hdim / 64, BT / 64), 256, 0, stream>>>(
        enc_out, Hdim, W_attn, 1024, h0, encp, Hdim, Hdim, 0);

    // 4. GRU: 64 sequential steps
    for (int t = 0; t < Tdim; ++t) {
        const float* hin  = (t & 1) ? h1 : h0;
        float*       hout = (t & 1) ? h0 : h1;
        gru_step_kernel<<<128, 192, 0, stream>>>(hin, hout, xp, W_hh, b_hh,
                                                 input_len, cat, t);
    }
    // final h is in h0 (t=63 odd writes h0)
    copy_kernel<<<32, 256, 0, stream>>>(h0, h_last, Bdim * Hdim);

    // 5. dec_p = dec_out @ Wd^T  (Wd = W_attn[:, 512:])  (1024 x 512, K=512)
    //    A = cat[:, :512] (lda=1024); bias = zeros (h0 is NOT zero anymore!)
    //    -> zero a small scratch: reuse tail of dense buffer? dense not yet
    //    written; zero first 512 of dense, use as zero-bias.
    zero_kernel<<<2, 256, 0, stream>>>(dense, 512);
    gemm_f32<<<dim3(Hdim / 64, BT / 64), 256, 0, stream>>>(
        cat, 1024, W_attn + 512, 1024, dense, decp, Hdim, Hdim, 0);

    // 6. attention -> cat[:, 512:1024]
    attn_kernel<<<BT, 256, 0, stream>>>(encp, decp, enc_out, b_attn, v_w, v_b,
                                        enc_len, input_len, cat);

    // 7. dense = tanh(cat @ W_dense^T + b_dense)   (1024 x 512, K=1024)
    gemm_f32<<<dim3(Hdim / 64, BT / 64), 256, 0, stream>>>(
        cat, 1024, W_dense, 1024, b_dense, dense, Hdim, 1024, 1);

    // 8. dense -> bf16
    f32_to_bf16_kernel<<<512, 256, 0, stream>>>(dense, dense_bf, BT * Hdim);

    // 9. logits = dense @ W_out^T + b_out   (1024 x 32000, K=512) bf16 MFMA
    gemm_logits<<<dim3(Vdim / 128, BT / 128), 256, 0, stream>>>(
        dense_bf, Wout_bf, b_out, logits);
}